// Round 1
// baseline (227.328 us; speedup 1.0000x reference)
//
#include <hip/hip_runtime.h>
#include <hip/hip_bf16.h>
#include <math.h>

#define Bsz 8
#define Hh 64
#define Ww 64
#define Cc 256
#define Nn 64
#define Ll 4096      /* Hh*Ww */
#define EPSf 1e-5f

__device__ __forceinline__ float ad_val(float a, float snr) {
    float s = fminf(fmaxf(snr, 0.f), 1.f);
    float scale = 0.6f + 0.4f * s;
    float v = tanhf(a) * scale;
    return fminf(fmaxf(v, -0.99f), 0.99f);
}

// K1: fused double-LayerNorm + input projection (u = z @ W_in^T, Bu = Bp*u)
// 512 blocks x 256 threads; block handles 64 consecutive positions.
__global__ __launch_bounds__(256) void k1_ln_gemm(
    const float* __restrict__ x, const float* __restrict__ Win,
    const float* __restrict__ Bp, float* __restrict__ Bu)
{
    __shared__ float zs[64 * 132];          // 64 rows x 128-k half-tile, pad->132
    __shared__ float mrow[64], srow[64];
    const int t = threadIdx.x;
    const int lane = t & 63;
    const int wv = __builtin_amdgcn_readfirstlane(t >> 6);
    const long pbase = (long)blockIdx.x * 64;
    const float* xt = x + pbase * Cc;

    // per-row stats (wave w handles rows 16w..16w+15, lanes span C as float4)
    for (int rr = 0; rr < 16; ++rr) {
        int r = wv * 16 + rr;
        float4 v = ((const float4*)(xt + (long)r * Cc))[lane];
        float s = v.x + v.y + v.z + v.w;
        float q = v.x*v.x + v.y*v.y + v.z*v.z + v.w*v.w;
        #pragma unroll
        for (int off = 32; off > 0; off >>= 1) {
            s += __shfl_down(s, off);
            q += __shfl_down(q, off);
        }
        if (lane == 0) {
            float m = s * (1.f/256.f);
            float var = fmaxf(q * (1.f/256.f) - m*m, 0.f);
            float r1 = rsqrtf(var + EPSf);
            float v2 = var / (var + EPSf);     // variance after first LN
            mrow[r] = m;
            srow[r] = r1 * rsqrtf(v2 + EPSf);  // combined LN(LN(.)) scale
        }
    }
    __syncthreads();

    float acc[16];
    #pragma unroll
    for (int j = 0; j < 16; ++j) acc[j] = 0.f;

    for (int half = 0; half < 2; ++half) {
        // load + normalize one k-half into LDS
        for (int i = t; i < 2048; i += 256) {   // float4 units: 64 rows x 32
            int row = i >> 5;
            int c4 = (i & 31);
            float4 v = ((const float4*)(xt + (long)row * Cc + half * 128))[c4];
            float m = mrow[row], sc = srow[row];
            v.x = (v.x - m) * sc; v.y = (v.y - m) * sc;
            v.z = (v.z - m) * sc; v.w = (v.w - m) * sc;
            *((float4*)&zs[row * 132 + c4 * 4]) = v;
        }
        __syncthreads();
        // GEMM: lane = row, wave w covers n in [16w,16w+16)
        const float* Wb = Win + (long)(wv * 16) * Cc + half * 128;
        for (int k = 0; k < 128; k += 4) {
            float4 z4 = *((const float4*)&zs[lane * 132 + k]);
            #pragma unroll
            for (int j = 0; j < 16; ++j) {
                const float* wr = Wb + j * Cc + k;   // wave-uniform -> s_load
                acc[j] = fmaf(z4.w, wr[3], fmaf(z4.z, wr[2],
                          fmaf(z4.y, wr[1], fmaf(z4.x, wr[0], acc[j]))));
            }
        }
        __syncthreads();
    }
    float* bu = Bu + (pbase + lane) * Nn + wv * 16;
    #pragma unroll
    for (int j = 0; j < 16; ++j) bu[j] = acc[j] * Bp[wv * 16 + j];
}

// K2: phase-1 chunk carries for all 4 directions.
// blocks 0..511: row tiles (b, j);  512..1023: col tiles (b, w=j). 64 thr.
__global__ __launch_bounds__(64) void k2_carry(
    const float* __restrict__ Bu, const float* __restrict__ A,
    const float* __restrict__ snr, float* __restrict__ E)
{
    __shared__ float tile[64 * 65];
    const int lane = threadIdx.x;
    const int id = blockIdx.x;
    const int isCol = id >> 9;
    const int b = (id >> 6) & 7;
    const int j = id & 63;
    const float Ad = ad_val(A[lane], snr[b]);
    const float* src = Bu + ((long)b * Ll + (isCol ? j : j * 64)) * Nn;
    const long stride = isCol ? (long)Ww * Nn : Nn;
    for (int k = 0; k < 64; ++k)
        tile[k * 65 + lane] = src[k * stride + lane];
    __syncthreads();
    float s = 0.f;
    #pragma unroll 8
    for (int k = 0; k < 64; ++k) s = fmaf(Ad, s, tile[k * 65 + lane]);
    const int dF = isCol ? 2 : 0;
    E[((dF * 8 + b) * 64 + j) * 64 + lane] = s;
    s = 0.f;
    #pragma unroll 8
    for (int k = 63; k >= 0; --k) s = fmaf(Ad, s, tile[k * 65 + lane]);
    E[(((dF + 1) * 8 + b) * 64 + (63 - j)) * 64 + lane] = s;
}

// K3: exclusive scan of chunk carries, 32 blocks (dir*8+b) x 64 threads.
__global__ __launch_bounds__(64) void k3_scan_carries(
    const float* __restrict__ E, float* __restrict__ Hx,
    const float* __restrict__ A, const float* __restrict__ snr)
{
    const int lane = threadIdx.x;
    const int db = blockIdx.x;          // dir*8 + b
    const int b = db & 7;
    float Ad = ad_val(A[lane], snr[b]);
    float p = Ad;
    #pragma unroll
    for (int i = 0; i < 6; ++i) p *= p;  // Ad^64
    float s = 0.f;
    const float* e = E + (long)db * 64 * 64;
    float* h = Hx + (long)db * 64 * 64;
    for (int jj = 0; jj < 64; ++jj) {
        h[jj * 64 + lane] = s;
        s = fmaf(p, s, e[jj * 64 + lane]);
    }
}

// K4: phase-3 — rescan with prefixes, combine fwd+bwd, scale by 0.25*Cp.
// Row blocks write Srow, col blocks write Scol (separate buffers: no race).
__global__ __launch_bounds__(64) void k4_apply(
    const float* __restrict__ Bu, const float* __restrict__ Hx,
    const float* __restrict__ A, const float* __restrict__ snr,
    const float* __restrict__ Cp, float* __restrict__ Srow,
    float* __restrict__ Scol)
{
    __shared__ float tile[64 * 65];
    __shared__ float hf[64 * 65];
    const int lane = threadIdx.x;
    const int id = blockIdx.x;
    const int isCol = id >> 9;
    const int b = (id >> 6) & 7;
    const int j = id & 63;
    const float Ad = ad_val(A[lane], snr[b]);
    const float cp = 0.25f * Cp[lane];
    const float* src = Bu + ((long)b * Ll + (isCol ? j : j * 64)) * Nn;
    const long stride = isCol ? (long)Ww * Nn : Nn;
    for (int k = 0; k < 64; ++k)
        tile[k * 65 + lane] = src[k * stride + lane];
    __syncthreads();
    const int dF = isCol ? 2 : 0;
    float s = Hx[((dF * 8 + b) * 64 + j) * 64 + lane];
    for (int k = 0; k < 64; ++k) {
        s = fmaf(Ad, s, tile[k * 65 + lane]);
        hf[k * 65 + lane] = s;      // same-lane readback, no barrier needed
    }
    float sb = Hx[(((dF + 1) * 8 + b) * 64 + (63 - j)) * 64 + lane];
    float* out0 = (isCol ? Scol : Srow) + ((long)b * Ll + (isCol ? j : j * 64)) * Nn;
    for (int k = 63; k >= 0; --k) {
        sb = fmaf(Ad, sb, tile[k * 65 + lane]);
        out0[k * stride + lane] = cp * (sb + hf[k * 65 + lane]);
    }
}

// K5: output projection y = S @ W_out^T + D*z, z recomputed from x.
// 512 blocks x 256 threads, 64 positions per block.
__global__ __launch_bounds__(256) void k5_gemm_out(
    const float* __restrict__ Srow, const float* __restrict__ Scol,
    const float* __restrict__ x, const float* __restrict__ Wout,
    const float* __restrict__ Dp, float* __restrict__ out)
{
    __shared__ float ss[64 * 68];
    __shared__ float mrow[64], srow_[64];
    const int t = threadIdx.x;
    const int lane = t & 63;
    const int wv = __builtin_amdgcn_readfirstlane(t >> 6);
    const long pbase = (long)blockIdx.x * 64;

    const float4* Sr = (const float4*)(Srow + pbase * Nn);
    const float4* Sc = (const float4*)(Scol + pbase * Nn);
    for (int i = t; i < 1024; i += 256) {
        float4 a = Sr[i], c = Sc[i];
        int row = i >> 4;
        int c4 = (i & 15) * 4;
        *((float4*)&ss[row * 68 + c4]) =
            make_float4(a.x + c.x, a.y + c.y, a.z + c.z, a.w + c.w);
    }
    const float* xt = x + pbase * Cc;
    for (int rr = 0; rr < 16; ++rr) {
        int r = wv * 16 + rr;
        float4 v = ((const float4*)(xt + (long)r * Cc))[lane];
        float s = v.x + v.y + v.z + v.w;
        float q = v.x*v.x + v.y*v.y + v.z*v.z + v.w*v.w;
        #pragma unroll
        for (int off = 32; off > 0; off >>= 1) {
            s += __shfl_down(s, off);
            q += __shfl_down(q, off);
        }
        if (lane == 0) {
            float m = s * (1.f/256.f);
            float var = fmaxf(q * (1.f/256.f) - m*m, 0.f);
            float r1 = rsqrtf(var + EPSf);
            float v2 = var / (var + EPSf);
            mrow[r] = m;
            srow_[r] = r1 * rsqrtf(v2 + EPSf);
        }
    }
    __syncthreads();

    // GEMM: lane = row (position), wave w covers c in [64w, 64w+64)
    float acc[64];
    #pragma unroll
    for (int cc = 0; cc < 64; ++cc) acc[cc] = 0.f;
    for (int k = 0; k < 64; k += 4) {
        float4 s4 = *((const float4*)&ss[lane * 68 + k]);
        #pragma unroll
        for (int cc = 0; cc < 64; ++cc) {
            const float* wr = Wout + (long)(wv * 64 + cc) * Nn + k;  // uniform
            acc[cc] = fmaf(s4.w, wr[3], fmaf(s4.z, wr[2],
                       fmaf(s4.y, wr[1], fmaf(s4.x, wr[0], acc[cc]))));
        }
    }
    // epilogue: + D*z (z recomputed), store (L2 write-combines per-lane runs)
    const float m = mrow[lane], sc = srow_[lane];
    const float* xr = xt + (long)lane * Cc + wv * 64;
    float* outr = out + (pbase + lane) * Cc + wv * 64;
    #pragma unroll
    for (int cc = 0; cc < 64; ++cc) {
        float z = (xr[cc] - m) * sc;
        outr[cc] = acc[cc] + Dp[wv * 64 + cc] * z;
    }
}

extern "C" void kernel_launch(void* const* d_in, const int* in_sizes, int n_in,
                              void* d_out, int out_size, void* d_ws, size_t ws_size,
                              hipStream_t stream)
{
    const float* x    = (const float*)d_in[0];
    const float* snr  = (const float*)d_in[1];
    const float* A    = (const float*)d_in[2];
    const float* Bp   = (const float*)d_in[3];
    const float* Cp   = (const float*)d_in[4];
    const float* Dp   = (const float*)d_in[5];
    const float* Win  = (const float*)d_in[6];
    const float* Wout = (const float*)d_in[7];
    float* out = (float*)d_out;

    char* ws = (char*)d_ws;
    float* Bu   = (float*)(ws);                                   // 8 MiB
    float* Srow = (float*)(ws + (size_t)8  * 1024 * 1024);        // 8 MiB
    float* Scol = (float*)(ws + (size_t)16 * 1024 * 1024);        // 8 MiB
    float* E    = (float*)(ws + (size_t)24 * 1024 * 1024);        // 512 KiB
    float* Hx   = (float*)(ws + (size_t)24 * 1024 * 1024 + 512 * 1024);

    hipLaunchKernelGGL(k1_ln_gemm,      dim3(512),  dim3(256), 0, stream, x, Win, Bp, Bu);
    hipLaunchKernelGGL(k2_carry,        dim3(1024), dim3(64),  0, stream, Bu, A, snr, E);
    hipLaunchKernelGGL(k3_scan_carries, dim3(32),   dim3(64),  0, stream, E, Hx, A, snr);
    hipLaunchKernelGGL(k4_apply,        dim3(1024), dim3(64),  0, stream, Bu, Hx, A, snr, Cp, Srow, Scol);
    hipLaunchKernelGGL(k5_gemm_out,     dim3(512),  dim3(256), 0, stream, Srow, Scol, x, Wout, Dp, out);
}

// Round 2
// 191.847 us; speedup vs baseline: 1.1849x; 1.1849x over previous
//
#include <hip/hip_runtime.h>
#include <hip/hip_bf16.h>
#include <math.h>

#define Bsz 8
#define Hh 64
#define Ww 64
#define Cc 256
#define Nn 64
#define Ll 4096      /* Hh*Ww */
#define EPSf 1e-5f

__device__ __forceinline__ float ad_val(float a, float snr) {
    float s = fminf(fmaxf(snr, 0.f), 1.f);
    float scale = 0.6f + 0.4f * s;
    float v = tanhf(a) * scale;
    return fminf(fmaxf(v, -0.99f), 0.99f);
}

// K1: fused double-LayerNorm + input projection (u = z @ W_in^T, Bu = Bp*u)
// 512 blocks x 256 threads; block handles 64 consecutive positions.
// Also persists the combined LN stats (mean, scale) for k5's epilogue.
__global__ __launch_bounds__(256) void k1_ln_gemm(
    const float* __restrict__ x, const float* __restrict__ Win,
    const float* __restrict__ Bp, float* __restrict__ Bu,
    float* __restrict__ Mst, float* __restrict__ Sst)
{
    __shared__ float zs[64 * 132];          // 64 rows x 128-k half-tile, pad->132
    __shared__ float mrow[64], srow[64];
    const int t = threadIdx.x;
    const int lane = t & 63;
    const int wv = __builtin_amdgcn_readfirstlane(t >> 6);
    const long pbase = (long)blockIdx.x * 64;
    const float* xt = x + pbase * Cc;

    // per-row stats (wave w handles rows 16w..16w+15, lanes span C as float4)
    for (int rr = 0; rr < 16; ++rr) {
        int r = wv * 16 + rr;
        float4 v = ((const float4*)(xt + (long)r * Cc))[lane];
        float s = v.x + v.y + v.z + v.w;
        float q = v.x*v.x + v.y*v.y + v.z*v.z + v.w*v.w;
        #pragma unroll
        for (int off = 32; off > 0; off >>= 1) {
            s += __shfl_down(s, off);
            q += __shfl_down(q, off);
        }
        if (lane == 0) {
            float m = s * (1.f/256.f);
            float var = fmaxf(q * (1.f/256.f) - m*m, 0.f);
            float r1 = rsqrtf(var + EPSf);
            float v2 = var / (var + EPSf);     // variance after first LN
            float sc = r1 * rsqrtf(v2 + EPSf); // combined LN(LN(.)) scale
            mrow[r] = m;
            srow[r] = sc;
            Mst[pbase + r] = m;
            Sst[pbase + r] = sc;
        }
    }
    __syncthreads();

    float acc[16];
    #pragma unroll
    for (int j = 0; j < 16; ++j) acc[j] = 0.f;

    for (int half = 0; half < 2; ++half) {
        // load + normalize one k-half into LDS
        for (int i = t; i < 2048; i += 256) {   // float4 units: 64 rows x 32
            int row = i >> 5;
            int c4 = (i & 31);
            float4 v = ((const float4*)(xt + (long)row * Cc + half * 128))[c4];
            float m = mrow[row], sc = srow[row];
            v.x = (v.x - m) * sc; v.y = (v.y - m) * sc;
            v.z = (v.z - m) * sc; v.w = (v.w - m) * sc;
            *((float4*)&zs[row * 132 + c4 * 4]) = v;
        }
        __syncthreads();
        // GEMM: lane = row, wave w covers n in [16w,16w+16)
        const float* Wb = Win + (long)(wv * 16) * Cc + half * 128;
        for (int k = 0; k < 128; k += 4) {
            float4 z4 = *((const float4*)&zs[lane * 132 + k]);
            #pragma unroll
            for (int j = 0; j < 16; ++j) {
                const float* wr = Wb + j * Cc + k;   // wave-uniform -> s_load
                acc[j] = fmaf(z4.w, wr[3], fmaf(z4.z, wr[2],
                          fmaf(z4.y, wr[1], fmaf(z4.x, wr[0], acc[j]))));
            }
        }
        __syncthreads();
    }
    float* bu = Bu + (pbase + lane) * Nn + wv * 16;
    #pragma unroll
    for (int j = 0; j < 16; ++j) bu[j] = acc[j] * Bp[wv * 16 + j];
}

// K2: phase-1 chunk carries for all 4 directions.
// blocks 0..511: row tiles (b, j);  512..1023: col tiles (b, w=j). 64 thr.
__global__ __launch_bounds__(64) void k2_carry(
    const float* __restrict__ Bu, const float* __restrict__ A,
    const float* __restrict__ snr, float* __restrict__ E)
{
    __shared__ float tile[64 * 65];
    const int lane = threadIdx.x;
    const int id = blockIdx.x;
    const int isCol = id >> 9;
    const int b = (id >> 6) & 7;
    const int j = id & 63;
    const float Ad = ad_val(A[lane], snr[b]);
    const float* src = Bu + ((long)b * Ll + (isCol ? j : j * 64)) * Nn;
    const long stride = isCol ? (long)Ww * Nn : Nn;
    for (int k = 0; k < 64; ++k)
        tile[k * 65 + lane] = src[k * stride + lane];
    __syncthreads();
    float s = 0.f;
    #pragma unroll 8
    for (int k = 0; k < 64; ++k) s = fmaf(Ad, s, tile[k * 65 + lane]);
    const int dF = isCol ? 2 : 0;
    E[((dF * 8 + b) * 64 + j) * 64 + lane] = s;
    s = 0.f;
    #pragma unroll 8
    for (int k = 63; k >= 0; --k) s = fmaf(Ad, s, tile[k * 65 + lane]);
    E[(((dF + 1) * 8 + b) * 64 + (63 - j)) * 64 + lane] = s;
}

// K3: exclusive scan of chunk carries, 32 blocks (dir*8+b) x 64 threads.
__global__ __launch_bounds__(64) void k3_scan_carries(
    const float* __restrict__ E, float* __restrict__ Hx,
    const float* __restrict__ A, const float* __restrict__ snr)
{
    const int lane = threadIdx.x;
    const int db = blockIdx.x;          // dir*8 + b
    const int b = db & 7;
    float Ad = ad_val(A[lane], snr[b]);
    float p = Ad;
    #pragma unroll
    for (int i = 0; i < 6; ++i) p *= p;  // Ad^64
    float s = 0.f;
    const float* e = E + (long)db * 64 * 64;
    float* h = Hx + (long)db * 64 * 64;
    for (int jj = 0; jj < 64; ++jj) {
        h[jj * 64 + lane] = s;
        s = fmaf(p, s, e[jj * 64 + lane]);
    }
}

// K4: phase-3 — rescan with prefixes, combine fwd+bwd, scale by 0.25*Cp.
// Row blocks write Srow, col blocks write Scol (separate buffers: no race).
__global__ __launch_bounds__(64) void k4_apply(
    const float* __restrict__ Bu, const float* __restrict__ Hx,
    const float* __restrict__ A, const float* __restrict__ snr,
    const float* __restrict__ Cp, float* __restrict__ Srow,
    float* __restrict__ Scol)
{
    __shared__ float tile[64 * 65];
    __shared__ float hf[64 * 65];
    const int lane = threadIdx.x;
    const int id = blockIdx.x;
    const int isCol = id >> 9;
    const int b = (id >> 6) & 7;
    const int j = id & 63;
    const float Ad = ad_val(A[lane], snr[b]);
    const float cp = 0.25f * Cp[lane];
    const float* src = Bu + ((long)b * Ll + (isCol ? j : j * 64)) * Nn;
    const long stride = isCol ? (long)Ww * Nn : Nn;
    for (int k = 0; k < 64; ++k)
        tile[k * 65 + lane] = src[k * stride + lane];
    __syncthreads();
    const int dF = isCol ? 2 : 0;
    float s = Hx[((dF * 8 + b) * 64 + j) * 64 + lane];
    for (int k = 0; k < 64; ++k) {
        s = fmaf(Ad, s, tile[k * 65 + lane]);
        hf[k * 65 + lane] = s;      // same-lane readback, no barrier needed
    }
    float sb = Hx[(((dF + 1) * 8 + b) * 64 + (63 - j)) * 64 + lane];
    float* out0 = (isCol ? Scol : Srow) + ((long)b * Ll + (isCol ? j : j * 64)) * Nn;
    for (int k = 63; k >= 0; --k) {
        sb = fmaf(Ad, sb, tile[k * 65 + lane]);
        out0[k * stride + lane] = cp * (sb + hf[k * 65 + lane]);
    }
}

// K5: output projection y = S @ W_out^T + D*z.
// 2048 blocks x 256 threads. Block = 64 positions x 64 channels
// (cq = blockIdx.x & 3 selects the channel quarter). Each wave: 64 pos x 16 c,
// acc[16] in VGPRs; per-lane S vector (64 floats) held in 16 float4 regs.
// Epilogue transposes through XOR-swizzled LDS so x-read + store are coalesced.
__global__ __launch_bounds__(256) void k5_gemm_out(
    const float* __restrict__ Srow, const float* __restrict__ Scol,
    const float* __restrict__ x, const float* __restrict__ Wout,
    const float* __restrict__ Dp, const float* __restrict__ Mst,
    const float* __restrict__ Sst, float* __restrict__ out)
{
    __shared__ float ss2[64 * 64];
    const int t = threadIdx.x;
    const int lane = t & 63;
    const int wv = __builtin_amdgcn_readfirstlane(t >> 6);
    const int cq = blockIdx.x & 3;
    const long pbase = (long)(blockIdx.x >> 2) * 64;

    // per-lane S = Srow + Scol for position (pbase+lane), 64 floats in regs
    const float4* Sr = (const float4*)(Srow + (pbase + lane) * Nn);
    const float4* Sc = (const float4*)(Scol + (pbase + lane) * Nn);
    float4 sreg[16];
    #pragma unroll
    for (int k4 = 0; k4 < 16; ++k4) {
        float4 a = Sr[k4], c = Sc[k4];
        sreg[k4] = make_float4(a.x + c.x, a.y + c.y, a.z + c.z, a.w + c.w);
    }

    float acc[16];
    #pragma unroll
    for (int j = 0; j < 16; ++j) acc[j] = 0.f;

    // GEMM: out channel c = cq*64 + wv*16 + j; Wout row is wave-uniform.
    const float* Wb = Wout + (long)(cq * 64 + wv * 16) * Nn;
    #pragma unroll
    for (int k4 = 0; k4 < 16; ++k4) {
        float4 s4 = sreg[k4];
        #pragma unroll
        for (int j = 0; j < 16; ++j) {
            const float* wr = Wb + j * Nn + k4 * 4;   // wave-uniform -> s_load
            acc[j] = fmaf(s4.w, wr[3], fmaf(s4.z, wr[2],
                      fmaf(s4.y, wr[1], fmaf(s4.x, wr[0], acc[j]))));
        }
    }

    // transpose via XOR-swizzled LDS (write: lane=pos; read: lane=channel)
    #pragma unroll
    for (int j = 0; j < 16; ++j) {
        int c = wv * 16 + j;
        ss2[lane * 64 + (c ^ (lane & 31))] = acc[j];
    }
    __syncthreads();

    const float dch = Dp[cq * 64 + lane];
    #pragma unroll 4
    for (int rr = 0; rr < 16; ++rr) {
        int pos = wv * 16 + rr;
        float v = ss2[pos * 64 + (lane ^ (pos & 31))];
        float m = Mst[pbase + pos];      // wave-uniform -> s_load
        float sg = Sst[pbase + pos];
        long off = (pbase + pos) * Cc + cq * 64 + lane;   // coalesced
        float z = (x[off] - m) * sg;
        out[off] = v + dch * z;
    }
}

extern "C" void kernel_launch(void* const* d_in, const int* in_sizes, int n_in,
                              void* d_out, int out_size, void* d_ws, size_t ws_size,
                              hipStream_t stream)
{
    const float* x    = (const float*)d_in[0];
    const float* snr  = (const float*)d_in[1];
    const float* A    = (const float*)d_in[2];
    const float* Bp   = (const float*)d_in[3];
    const float* Cp   = (const float*)d_in[4];
    const float* Dp   = (const float*)d_in[5];
    const float* Win  = (const float*)d_in[6];
    const float* Wout = (const float*)d_in[7];
    float* out = (float*)d_out;

    char* ws = (char*)d_ws;
    float* Bu   = (float*)(ws);                                   // 8 MiB
    float* Srow = (float*)(ws + (size_t)8  * 1024 * 1024);        // 8 MiB
    float* Scol = (float*)(ws + (size_t)16 * 1024 * 1024);        // 8 MiB
    float* E    = (float*)(ws + (size_t)24 * 1024 * 1024);        // 512 KiB
    float* Hx   = (float*)(ws + (size_t)24 * 1024 * 1024 + 512 * 1024);   // 512 KiB
    float* Mst  = (float*)(ws + (size_t)25 * 1024 * 1024);        // 128 KiB
    float* Sst  = (float*)(ws + (size_t)25 * 1024 * 1024 + 128 * 1024);   // 128 KiB

    hipLaunchKernelGGL(k1_ln_gemm,      dim3(512),  dim3(256), 0, stream, x, Win, Bp, Bu, Mst, Sst);
    hipLaunchKernelGGL(k2_carry,        dim3(1024), dim3(64),  0, stream, Bu, A, snr, E);
    hipLaunchKernelGGL(k3_scan_carries, dim3(32),   dim3(64),  0, stream, E, Hx, A, snr);
    hipLaunchKernelGGL(k4_apply,        dim3(1024), dim3(64),  0, stream, Bu, Hx, A, snr, Cp, Srow, Scol);
    hipLaunchKernelGGL(k5_gemm_out,     dim3(2048), dim3(256), 0, stream, Srow, Scol, x, Wout, Dp, Mst, Sst, out);
}

// Round 3
// 155.611 us; speedup vs baseline: 1.4609x; 1.2329x over previous
//
#include <hip/hip_runtime.h>
#include <hip/hip_bf16.h>
#include <math.h>

#define Bsz 8
#define Hh 64
#define Ww 64
#define Cc 256
#define Nn 64
#define Ll 4096      /* Hh*Ww */
#define EPSf 1e-5f

typedef __bf16 v8bf __attribute__((ext_vector_type(8)));
typedef float  f32x4 __attribute__((ext_vector_type(4)));

__device__ __forceinline__ float ad_val(float a, float snr) {
    float s = fminf(fmaxf(snr, 0.f), 1.f);
    float scale = 0.6f + 0.4f * s;
    float v = tanhf(a) * scale;
    return fminf(fmaxf(v, -0.99f), 0.99f);
}

// K0: pre-convert weights to bf16 MFMA B-fragment order; precompute Wsum*Bp.
// B-frag for 16x16x32: lane holds B[k=(lane>>4)*8+j][n=lane&15], j=0..7.
// Tile storage: [(ktile*NT + ntile)*64 + lane]*8 + j  (16B per lane -> v8bf).
__global__ __launch_bounds__(256) void k0_weights(
    const float* __restrict__ Win, const float* __restrict__ Wout,
    const float* __restrict__ Bp, __bf16* __restrict__ Wh,
    __bf16* __restrict__ Wl, __bf16* __restrict__ Wo, float* __restrict__ WB)
{
    const int t = threadIdx.x;
    // W_in: K=256 (8 ktiles) x N=64 (4 ntiles); B[k][n] = Win[n][k]. hi+lo split.
    for (int idx = t; idx < 32 * 64; idx += 256) {
        int tile = idx >> 6, lane = idx & 63;
        int kt = tile >> 2, nt = tile & 3;
        int q = lane >> 4, n = nt * 16 + (lane & 15);
        #pragma unroll
        for (int j = 0; j < 8; ++j) {
            int k = kt * 32 + q * 8 + j;
            float w = Win[n * Cc + k];
            __bf16 h = (__bf16)w;
            Wh[idx * 8 + j] = h;
            Wl[idx * 8 + j] = (__bf16)(w - (float)h);
        }
    }
    // W_out: K=64 (2 ktiles) x N=256 (16 ntiles); B[k][c] = Wout[c][k].
    for (int idx = t; idx < 32 * 64; idx += 256) {
        int tile = idx >> 6, lane = idx & 63;
        int kt = tile >> 4, ntg = tile & 15;
        int q = lane >> 4, c = ntg * 16 + (lane & 15);
        #pragma unroll
        for (int j = 0; j < 8; ++j) {
            int k = kt * 32 + q * 8 + j;
            Wo[idx * 8 + j] = (__bf16)Wout[c * Nn + k];
        }
    }
    if (t < 64) {
        float s = 0.f;
        for (int c2 = 0; c2 < Cc; ++c2) s += Win[t * Cc + c2];
        WB[t] = s * Bp[t];
    }
}

// K1: LN stats + MFMA GEMM on RAW x (LN folded into epilogue by linearity):
//   u[p][n] = s[p]*( (x@Win^T)[p][n] - m[p]*Wsum[n] );  Bu = Bp[n]*u.
// 512 blocks x 256 thr; block = 64 positions; wave wv = mtile (16 pos) x 64 n.
// 2-term bf16 split GEMM (xh*Wh + xl*Wh + xh*Wl) ~ fp32 accuracy.
__global__ __launch_bounds__(256) void k1_ln_gemm(
    const float* __restrict__ x, const __bf16* __restrict__ Wh,
    const __bf16* __restrict__ Wl, const float* __restrict__ Bp,
    const float* __restrict__ WB, float* __restrict__ Bu,
    float* __restrict__ Mst, float* __restrict__ Sst)
{
    __shared__ float mrow[64], srow[64];
    const int t = threadIdx.x;
    const int lane = t & 63;
    const int wv = __builtin_amdgcn_readfirstlane(t >> 6);
    const long pbase = (long)blockIdx.x * 64;
    const float* xt = x + pbase * Cc;

    // per-row LN stats (wave wv: rows 16wv..16wv+15; lanes span C as float4)
    for (int rr = 0; rr < 16; ++rr) {
        int r = wv * 16 + rr;
        float4 v = ((const float4*)(xt + (long)r * Cc))[lane];
        float s = v.x + v.y + v.z + v.w;
        float q = v.x*v.x + v.y*v.y + v.z*v.z + v.w*v.w;
        #pragma unroll
        for (int off = 32; off > 0; off >>= 1) {
            s += __shfl_down(s, off);
            q += __shfl_down(q, off);
        }
        if (lane == 0) {
            float m = s * (1.f/256.f);
            float var = fmaxf(q * (1.f/256.f) - m*m, 0.f);
            float r1 = rsqrtf(var + EPSf);
            float v2 = var / (var + EPSf);     // variance after first LN
            float sc = r1 * rsqrtf(v2 + EPSf); // combined LN(LN(.)) scale
            mrow[r] = m;
            srow[r] = sc;
            Mst[pbase + r] = m;
            Sst[pbase + r] = sc;
        }
    }
    __syncthreads();

    const int q = lane >> 4;
    const int mi = lane & 15;
    const float* xa = xt + (long)(wv * 16 + mi) * Cc + q * 8;

    f32x4 acc[4];
    #pragma unroll
    for (int nt = 0; nt < 4; ++nt) acc[nt] = (f32x4){0.f, 0.f, 0.f, 0.f};

    #pragma unroll
    for (int kt = 0; kt < 8; ++kt) {
        float4 a0 = *(const float4*)(xa + kt * 32);
        float4 a1 = *(const float4*)(xa + kt * 32 + 4);
        float av[8] = {a0.x, a0.y, a0.z, a0.w, a1.x, a1.y, a1.z, a1.w};
        v8bf ah, al;
        #pragma unroll
        for (int j = 0; j < 8; ++j) {
            __bf16 h = (__bf16)av[j];
            ah[j] = h;
            al[j] = (__bf16)(av[j] - (float)h);
        }
        #pragma unroll
        for (int nt = 0; nt < 4; ++nt) {
            v8bf bh = *(const v8bf*)(Wh + ((long)(kt * 4 + nt) * 64 + lane) * 8);
            v8bf bl = *(const v8bf*)(Wl + ((long)(kt * 4 + nt) * 64 + lane) * 8);
            acc[nt] = __builtin_amdgcn_mfma_f32_16x16x32_bf16(ah, bh, acc[nt], 0, 0, 0);
            acc[nt] = __builtin_amdgcn_mfma_f32_16x16x32_bf16(al, bh, acc[nt], 0, 0, 0);
            acc[nt] = __builtin_amdgcn_mfma_f32_16x16x32_bf16(ah, bl, acc[nt], 0, 0, 0);
        }
    }

    // epilogue: C/D layout row=(lane>>4)*4+reg (=pos), col=lane&15 (=n)
    #pragma unroll
    for (int nt = 0; nt < 4; ++nt) {
        int n = nt * 16 + mi;
        float bpn = Bp[n];
        float wbn = WB[n];
        #pragma unroll
        for (int reg = 0; reg < 4; ++reg) {
            int p = wv * 16 + q * 4 + reg;
            float m = mrow[p], s = srow[p];
            Bu[(pbase + p) * Nn + n] = s * (acc[nt][reg] * bpn - m * wbn);
        }
    }
}

// K2: phase-1 chunk carries for all 4 directions.
// blocks 0..511: row tiles (b, j);  512..1023: col tiles (b, w=j). 64 thr.
__global__ __launch_bounds__(64) void k2_carry(
    const float* __restrict__ Bu, const float* __restrict__ A,
    const float* __restrict__ snr, float* __restrict__ E)
{
    __shared__ float tile[64 * 65];
    const int lane = threadIdx.x;
    const int id = blockIdx.x;
    const int isCol = id >> 9;
    const int b = (id >> 6) & 7;
    const int j = id & 63;
    const float Ad = ad_val(A[lane], snr[b]);
    const float* src = Bu + ((long)b * Ll + (isCol ? j : j * 64)) * Nn;
    const long stride = isCol ? (long)Ww * Nn : Nn;
    for (int k = 0; k < 64; ++k)
        tile[k * 65 + lane] = src[k * stride + lane];
    __syncthreads();
    float s = 0.f;
    #pragma unroll 8
    for (int k = 0; k < 64; ++k) s = fmaf(Ad, s, tile[k * 65 + lane]);
    const int dF = isCol ? 2 : 0;
    E[((dF * 8 + b) * 64 + j) * 64 + lane] = s;
    s = 0.f;
    #pragma unroll 8
    for (int k = 63; k >= 0; --k) s = fmaf(Ad, s, tile[k * 65 + lane]);
    E[(((dF + 1) * 8 + b) * 64 + (63 - j)) * 64 + lane] = s;
}

// K3: exclusive scan of chunk carries, 32 blocks (dir*8+b) x 64 threads.
__global__ __launch_bounds__(64) void k3_scan_carries(
    const float* __restrict__ E, float* __restrict__ Hx,
    const float* __restrict__ A, const float* __restrict__ snr)
{
    const int lane = threadIdx.x;
    const int db = blockIdx.x;          // dir*8 + b
    const int b = db & 7;
    float Ad = ad_val(A[lane], snr[b]);
    float p = Ad;
    #pragma unroll
    for (int i = 0; i < 6; ++i) p *= p;  // Ad^64
    float s = 0.f;
    const float* e = E + (long)db * 64 * 64;
    float* h = Hx + (long)db * 64 * 64;
    for (int jj = 0; jj < 64; ++jj) {
        h[jj * 64 + lane] = s;
        s = fmaf(p, s, e[jj * 64 + lane]);
    }
}

// K4: phase-3 — rescan with prefixes, combine fwd+bwd, scale by 0.25*Cp.
__global__ __launch_bounds__(64) void k4_apply(
    const float* __restrict__ Bu, const float* __restrict__ Hx,
    const float* __restrict__ A, const float* __restrict__ snr,
    const float* __restrict__ Cp, float* __restrict__ Srow,
    float* __restrict__ Scol)
{
    __shared__ float tile[64 * 65];
    __shared__ float hf[64 * 65];
    const int lane = threadIdx.x;
    const int id = blockIdx.x;
    const int isCol = id >> 9;
    const int b = (id >> 6) & 7;
    const int j = id & 63;
    const float Ad = ad_val(A[lane], snr[b]);
    const float cp = 0.25f * Cp[lane];
    const float* src = Bu + ((long)b * Ll + (isCol ? j : j * 64)) * Nn;
    const long stride = isCol ? (long)Ww * Nn : Nn;
    for (int k = 0; k < 64; ++k)
        tile[k * 65 + lane] = src[k * stride + lane];
    __syncthreads();
    const int dF = isCol ? 2 : 0;
    float s = Hx[((dF * 8 + b) * 64 + j) * 64 + lane];
    for (int k = 0; k < 64; ++k) {
        s = fmaf(Ad, s, tile[k * 65 + lane]);
        hf[k * 65 + lane] = s;      // same-lane readback, no barrier needed
    }
    float sb = Hx[(((dF + 1) * 8 + b) * 64 + (63 - j)) * 64 + lane];
    float* out0 = (isCol ? Scol : Srow) + ((long)b * Ll + (isCol ? j : j * 64)) * Nn;
    for (int k = 63; k >= 0; --k) {
        sb = fmaf(Ad, sb, tile[k * 65 + lane]);
        out0[k * stride + lane] = cp * (sb + hf[k * 65 + lane]);
    }
}

// K5: MFMA output projection y = S @ Wout^T + D*z, S = Srow+Scol (bf16).
// 1024 blocks x 256 thr; block = 32 pos x 256 ch.
// wave wv: mtile = wv>>1 (16 pos), nhalf = wv&1 (8 ntiles of 16 ch).
__global__ __launch_bounds__(256) void k5_gemm_out(
    const float* __restrict__ Srow, const float* __restrict__ Scol,
    const float* __restrict__ x, const __bf16* __restrict__ Wo,
    const float* __restrict__ Dp, const float* __restrict__ Mst,
    const float* __restrict__ Sst, float* __restrict__ out)
{
    const int t = threadIdx.x;
    const int lane = t & 63;
    const int wv = __builtin_amdgcn_readfirstlane(t >> 6);
    const int mtile = wv >> 1;
    const int nh = wv & 1;
    const long pbase = (long)blockIdx.x * 32;
    const int q = lane >> 4;
    const int mi = lane & 15;

    const float* sr = Srow + (pbase + mtile * 16 + mi) * Nn + q * 8;
    const float* sc = Scol + (pbase + mtile * 16 + mi) * Nn + q * 8;

    f32x4 acc[8];
    #pragma unroll
    for (int nt = 0; nt < 8; ++nt) acc[nt] = (f32x4){0.f, 0.f, 0.f, 0.f};

    #pragma unroll
    for (int kt = 0; kt < 2; ++kt) {
        float4 r0 = *(const float4*)(sr + kt * 32);
        float4 r1 = *(const float4*)(sr + kt * 32 + 4);
        float4 c0 = *(const float4*)(sc + kt * 32);
        float4 c1 = *(const float4*)(sc + kt * 32 + 4);
        float sv[8] = {r0.x + c0.x, r0.y + c0.y, r0.z + c0.z, r0.w + c0.w,
                       r1.x + c1.x, r1.y + c1.y, r1.z + c1.z, r1.w + c1.w};
        v8bf af;
        #pragma unroll
        for (int j = 0; j < 8; ++j) af[j] = (__bf16)sv[j];
        #pragma unroll
        for (int nt = 0; nt < 8; ++nt) {
            int ntg = nh * 8 + nt;
            v8bf b = *(const v8bf*)(Wo + ((long)(kt * 16 + ntg) * 64 + lane) * 8);
            acc[nt] = __builtin_amdgcn_mfma_f32_16x16x32_bf16(af, b, acc[nt], 0, 0, 0);
        }
    }

    // epilogue: + D*z with z recomputed from x and persisted LN stats
    #pragma unroll
    for (int nt = 0; nt < 8; ++nt) {
        int c = nh * 128 + nt * 16 + mi;
        float dc = Dp[c];
        #pragma unroll
        for (int reg = 0; reg < 4; ++reg) {
            long p = pbase + mtile * 16 + q * 4 + reg;
            float m = Mst[p], s = Sst[p];
            long off = p * Cc + c;
            out[off] = acc[nt][reg] + dc * ((x[off] - m) * s);
        }
    }
}

extern "C" void kernel_launch(void* const* d_in, const int* in_sizes, int n_in,
                              void* d_out, int out_size, void* d_ws, size_t ws_size,
                              hipStream_t stream)
{
    const float* x    = (const float*)d_in[0];
    const float* snr  = (const float*)d_in[1];
    const float* A    = (const float*)d_in[2];
    const float* Bp   = (const float*)d_in[3];
    const float* Cp   = (const float*)d_in[4];
    const float* Dp   = (const float*)d_in[5];
    const float* Win  = (const float*)d_in[6];
    const float* Wout = (const float*)d_in[7];
    float* out = (float*)d_out;

    char* ws = (char*)d_ws;
    float*  Bu   = (float*)(ws);                                       // 8 MiB
    float*  Srow = (float*)(ws + (size_t)8  * 1024 * 1024);            // 8 MiB
    float*  Scol = (float*)(ws + (size_t)16 * 1024 * 1024);            // 8 MiB
    float*  E    = (float*)(ws + (size_t)24 * 1024 * 1024);            // 512 KiB
    float*  Hx   = (float*)(ws + (size_t)24 * 1024 * 1024 + 512*1024); // 512 KiB
    float*  Mst  = (float*)(ws + (size_t)25 * 1024 * 1024);            // 128 KiB
    float*  Sst  = (float*)(ws + (size_t)25 * 1024 * 1024 + 128*1024); // 128 KiB
    char*   wbase = ws + (size_t)25 * 1024 * 1024 + 512 * 1024;
    __bf16* Wh   = (__bf16*)(wbase);                                   // 32 KiB
    __bf16* Wl   = (__bf16*)(wbase + 32 * 1024);                       // 32 KiB
    __bf16* Wo   = (__bf16*)(wbase + 64 * 1024);                       // 32 KiB
    float*  WB   = (float*)(wbase + 96 * 1024);                        // 256 B

    hipLaunchKernelGGL(k0_weights,      dim3(1),    dim3(256), 0, stream, Win, Wout, Bp, Wh, Wl, Wo, WB);
    hipLaunchKernelGGL(k1_ln_gemm,      dim3(512),  dim3(256), 0, stream, x, Wh, Wl, Bp, WB, Bu, Mst, Sst);
    hipLaunchKernelGGL(k2_carry,        dim3(1024), dim3(64),  0, stream, Bu, A, snr, E);
    hipLaunchKernelGGL(k3_scan_carries, dim3(32),   dim3(64),  0, stream, E, Hx, A, snr);
    hipLaunchKernelGGL(k4_apply,        dim3(1024), dim3(64),  0, stream, Bu, Hx, A, snr, Cp, Srow, Scol);
    hipLaunchKernelGGL(k5_gemm_out,     dim3(1024), dim3(256), 0, stream, Srow, Scol, x, Wo, Dp, Mst, Sst, out);
}